// Round 1
// baseline (192.490 us; speedup 1.0000x reference)
//
#include <hip/hip_runtime.h>

// MMoE: B=16384 D=512 U=128 E=16 T=4, fp32 in/out.
// Plan: gates in exact f32 (kernel 1, ws holds [B][T*E] = 4 MiB),
//       expert GEMM in bf16 MFMA fused with relu + gate contraction (kernel 2).

#define Bsz 16384
#define Dd  512
#define Uu  128
#define Ee  16
#define Tt  4
#define Nn  2048   // U*E flattened

typedef short bf16x8 __attribute__((ext_vector_type(8)));
typedef float f32x4 __attribute__((ext_vector_type(4)));

static __device__ __forceinline__ unsigned short f2bf(float f) {
    unsigned int u = __builtin_bit_cast(unsigned int, f);
    u += 0x7fffu + ((u >> 16) & 1u);   // round-to-nearest-even
    return (unsigned short)(u >> 16);
}
static __device__ __forceinline__ float bf2f(unsigned short s) {
    return __builtin_bit_cast(float, (unsigned int)s << 16);
}

// ---------------- Kernel 1: gate logits + softmax (exact f32) ----------------
// 16-lane group = (t = lane>>4, e = lane&15); each wave handles 4 consecutive rows.
__global__ __launch_bounds__(256) void gates_kernel(
        const float* __restrict__ x, const float* __restrict__ gk,
        const float* __restrict__ gb, float* __restrict__ gates) {
    const int wave = threadIdx.x >> 6, lane = threadIdx.x & 63;
    const int t = lane >> 4, e = lane & 15;
    const int b = blockIdx.x * 16 + wave * 4;
    const float* __restrict__ gkt = gk + (size_t)t * (Dd * Ee) + e;
    const float* __restrict__ xr = x + (size_t)b * Dd;
    float a0 = 0.f, a1 = 0.f, a2 = 0.f, a3 = 0.f;
    for (int d = 0; d < Dd; ++d) {
        float w = gkt[d * Ee];
        a0 = fmaf(xr[d], w, a0);
        a1 = fmaf(xr[Dd + d], w, a1);
        a2 = fmaf(xr[2 * Dd + d], w, a2);
        a3 = fmaf(xr[3 * Dd + d], w, a3);
    }
    const float bias = gb[t * Ee + e];
    float acc[4] = {a0 + bias, a1 + bias, a2 + bias, a3 + bias};
    #pragma unroll
    for (int r = 0; r < 4; ++r) {
        float a = acc[r];
        float m = a;
        m = fmaxf(m, __shfl_xor(m, 1));
        m = fmaxf(m, __shfl_xor(m, 2));
        m = fmaxf(m, __shfl_xor(m, 4));
        m = fmaxf(m, __shfl_xor(m, 8));
        float p = __expf(a - m);
        float s = p;
        s += __shfl_xor(s, 1);
        s += __shfl_xor(s, 2);
        s += __shfl_xor(s, 4);
        s += __shfl_xor(s, 8);
        gates[(size_t)(b + r) * 64 + lane] = p / s;  // layout [b][t*16+e]
    }
}

// ---------------- Kernel 2: expert GEMM (bf16 MFMA) + relu + gate contraction ----------------
#define BM 128
#define BN 256   // = 16 u's x 16 e's (n = u*16+e)
#define BK 64
#define LDA 72   // padded row stride (shorts); 144 B = multiple of 16 B
#define LDB 72
#define LDE 264

__global__ __launch_bounds__(512) void moe_kernel(
        const float* __restrict__ x, const float* __restrict__ ek,
        const float* __restrict__ eb, const float* __restrict__ gates,
        float* __restrict__ out) {
    // staging region (sA+sB = 55296 B) overlaid later by eo (67584 B)
    __shared__ __align__(16) unsigned short smem[BM * LDE];
    unsigned short* sA = smem;             // [BM][LDA]  A tile, bf16
    unsigned short* sB = smem + BM * LDA;  // [BN][LDB]  B tile TRANSPOSED: sB[n][k]

    const int tid = threadIdx.x;
    const int wave = tid >> 6, lane = tid & 63;
    const int llo = lane & 15, lhi = lane >> 4;
    const int b0 = blockIdx.y * BM;
    const int n0 = blockIdx.x * BN;
    const int mr = (wave >> 2) * 64;  // wave row origin (2 row-groups)
    const int nc = (wave & 3) * 64;   // wave col origin (4 col-groups)

    f32x4 acc[4][4] = {};

    for (int kt = 0; kt < Dd / BK; ++kt) {
        const int k0 = kt * BK;
        __syncthreads();  // previous tile fully consumed before overwrite
        // stage A: 128x64 f32 -> bf16; 2048 float4s over 512 threads
        #pragma unroll
        for (int i = 0; i < 4; ++i) {
            int f = i * 512 + tid;
            int row = f >> 4, c4 = (f & 15) * 4;
            const float4 v = *(const float4*)(x + (size_t)(b0 + row) * Dd + k0 + c4);
            ushort4 w;
            w.x = f2bf(v.x); w.y = f2bf(v.y); w.z = f2bf(v.z); w.w = f2bf(v.w);
            *(ushort4*)(sA + row * LDA + c4) = w;
        }
        // stage B transposed: sB[n][k] <- ek[k][n0+n]; tasks = 16 k-groups x 256 n
        #pragma unroll
        for (int i = 0; i < 8; ++i) {
            int f = i * 512 + tid;
            int kg = (f >> 8) * 4, n = f & 255;
            const float* p = ek + (size_t)(k0 + kg) * Nn + n0 + n;
            ushort4 w;
            w.x = f2bf(p[0]);
            w.y = f2bf(p[(size_t)Nn]);
            w.z = f2bf(p[2 * (size_t)Nn]);
            w.w = f2bf(p[3 * (size_t)Nn]);
            *(ushort4*)(sB + n * LDB + kg) = w;
        }
        __syncthreads();
        #pragma unroll
        for (int ks = 0; ks < BK; ks += 32) {
            bf16x8 aF[4], bF[4];
            #pragma unroll
            for (int mi = 0; mi < 4; ++mi)
                aF[mi] = *(const bf16x8*)(sA + (mr + mi * 16 + llo) * LDA + ks + lhi * 8);
            #pragma unroll
            for (int ni = 0; ni < 4; ++ni)
                bF[ni] = *(const bf16x8*)(sB + (nc + ni * 16 + llo) * LDB + ks + lhi * 8);
            #pragma unroll
            for (int mi = 0; mi < 4; ++mi)
                #pragma unroll
                for (int ni = 0; ni < 4; ++ni)
                    acc[mi][ni] = __builtin_amdgcn_mfma_f32_16x16x32_bf16(
                        aF[mi], bF[ni], acc[mi][ni], 0, 0, 0);
        }
    }

    __syncthreads();  // all MFMA reads done; safe to overlay eo on staging LDS
    unsigned short* eo = smem;  // [BM][LDE] bf16 expert tile (relu'd)
    #pragma unroll
    for (int ni = 0; ni < 4; ++ni) {
        const int col = nc + ni * 16 + llo;     // C frag: col = lane&15
        const float ebv = eb[n0 + col];         // flat [u][e] == n
        #pragma unroll
        for (int mi = 0; mi < 4; ++mi) {
            #pragma unroll
            for (int j = 0; j < 4; ++j) {
                int row = mr + mi * 16 + lhi * 4 + j;  // C frag: row = (lane>>4)*4+j
                eo[row * LDE + col] = f2bf(fmaxf(acc[mi][ni][j] + ebv, 0.f));
            }
        }
    }
    __syncthreads();
    // contraction: out[t,b,u] = sum_e eo[b,u,e] * gates[b][t*16+e]
    #pragma unroll
    for (int i = 0; i < 4; ++i) {
        int f = i * 512 + tid;
        int m = f >> 4, ul = f & 15;
        const unsigned short* er = eo + m * LDE + ul * 16;
        const float* gr = gates + (size_t)(b0 + m) * 64;
        float o0 = 0.f, o1 = 0.f, o2 = 0.f, o3 = 0.f;
        #pragma unroll
        for (int e = 0; e < 16; ++e) {
            float v = bf2f(er[e]);
            o0 = fmaf(v, gr[e], o0);
            o1 = fmaf(v, gr[16 + e], o1);
            o2 = fmaf(v, gr[32 + e], o2);
            o3 = fmaf(v, gr[48 + e], o3);
        }
        size_t base = (size_t)(b0 + m) * Uu + (n0 >> 4) + ul;
        out[base] = o0;
        out[(size_t)Bsz * Uu + base] = o1;
        out[2 * (size_t)Bsz * Uu + base] = o2;
        out[3 * (size_t)Bsz * Uu + base] = o3;
    }
}

extern "C" void kernel_launch(void* const* d_in, const int* in_sizes, int n_in,
                              void* d_out, int out_size, void* d_ws, size_t ws_size,
                              hipStream_t stream) {
    const float* x  = (const float*)d_in[0];
    const float* ek = (const float*)d_in[1];
    const float* eb = (const float*)d_in[2];
    const float* gk = (const float*)d_in[3];
    const float* gb = (const float*)d_in[4];
    float* out = (float*)d_out;
    float* gates = (float*)d_ws;  // needs 16384*64*4 = 4 MiB of ws

    gates_kernel<<<Bsz / 16, 256, 0, stream>>>(x, gk, gb, gates);
    moe_kernel<<<dim3(Nn / BN, Bsz / BM), 512, 0, stream>>>(x, ek, eb, gates, out);
}